// Round 6
// baseline (481.195 us; speedup 1.0000x reference)
//
#include <hip/hip_runtime.h>
#include <hip/hip_cooperative_groups.h>

namespace cg = cooperative_groups;

typedef unsigned short u16;
typedef short v8s __attribute__((ext_vector_type(8)));
typedef float v4f __attribute__((ext_vector_type(4)));

namespace {
constexpr int kC = 384;
constexpr int kN1 = 513;
constexpr int kH = 6;
constexpr int kBH = 48;      // B*H
constexpr int kRows = 4104;  // B*N1 tokens per half
constexpr int kRows2 = 8208; // B*M
constexpr int kPld = 576;    // Vt k-stride in bf16 elems (64*9)
constexpr int kGrid = 432;   // cooperative grid size
}  // namespace

__device__ __forceinline__ u16 f2b(float f) {
  unsigned int u = __float_as_uint(f);
  u += 0x7fffu + ((u >> 16) & 1u);
  return (u16)(u >> 16);
}

__device__ __forceinline__ int gumbel_argmax(const float* __restrict__ w,
                                             const float* __restrict__ g) {
  float v0 = w[0] + g[0], v1 = w[1] + g[1], v2 = w[2] + g[2], v3 = w[3] + g[3];
  int j = 0;
  float m = v0;
  if (v1 > m) { m = v1; j = 1; }
  if (v2 > m) { m = v2; j = 2; }
  if (v3 > m) { m = v3; j = 3; }
  return j;
}

// ---- phase: one 32x32 transpose+convert tile of the selected weights ----
__device__ __forceinline__ void phase_prep(
    u16* sm, int u, const float* Wq1, const float* Wq2, const float* Wk1,
    const float* Wk2, const float* Wv1, const float* Wv2, const float* Wo,
    int j, u16* Wqt, u16* Wkt, u16* Wv1t, u16* Wv2t, u16* Wot) {
  float (*tb)[33] = (float(*)[33])sm;
  const int tid = threadIdx.x;
  const int tx = tid & 31, ty = tid >> 5;
  const int z = u / 144, rem = u - z * 144;
  const int c0 = (rem % 12) * 32, r0 = (rem / 12) * 32;
  const float* src;
  u16* dst;
  switch (z) {
    case 0: src = (j < 2) ? Wq1 : Wq2; dst = Wqt; break;
    case 1: src = (j == 0 || j == 2) ? Wk1 : Wk2; dst = Wkt; break;
    case 2: src = Wv1; dst = Wv1t; break;
    case 3: src = Wv2; dst = Wv2t; break;
    default: src = Wo; dst = Wot; break;
  }
  for (int p = 0; p < 4; ++p)
    tb[ty + p * 8][tx] = src[(size_t)(r0 + ty + p * 8) * kC + c0 + tx];
  __syncthreads();
  for (int p = 0; p < 4; ++p)
    dst[(size_t)(c0 + ty + p * 8) * kC + r0 + tx] = f2b(tb[tx][ty + p * 8]);
  __syncthreads();  // tb safe to reuse on return
}

// ---- phase: one 128x128 tile of the fused QKV projections ----
// op0: Q = 0.125*(xsel @ Wq + bq); op1: K = xsel @ Wk + bk (natural layout)
// op2/3: Vt = (x @ Wv)^T as Vt[bh][d][kPld] (swapped-operand MFMA)
__device__ __forceinline__ void phase_qkv(
    u16* sm, int op, int mb33, int nb3, const float* x, const u16* Wqt,
    const u16* Wkt, const u16* Wv1t, const u16* Wv2t, const float* bq1,
    const float* bq2, const float* bk1, const float* bk2, const float* bv1,
    const float* bv2, int j, u16* Qb, u16* Kb, u16* Vt1, u16* Vt2) {
  u16 (*As)[72] = (u16(*)[72])sm;
  u16 (*Bs)[72] = (u16(*)[72])(sm + 9216);
  const bool vmode = (op >= 2);
  const float* bias;
  int xoff;
  const u16* Wt;
  if (op == 0) {
    bias = (j < 2) ? bq1 : bq2; xoff = (j < 2) ? 0 : kN1; Wt = Wqt;
  } else if (op == 1) {
    const bool u1 = (j == 0 || j == 2);
    bias = u1 ? bk1 : bk2; xoff = u1 ? 0 : kN1; Wt = Wkt;
  } else if (op == 2) {
    bias = bv1; xoff = 0; Wt = Wv1t;
  } else {
    bias = bv2; xoff = kN1; Wt = Wv2t;
  }
  const int m0 = (vmode ? nb3 : mb33) * 128;
  const int n0 = (vmode ? mb33 : nb3) * 128;
  const int tid = threadIdx.x;
  const int lane = tid & 63, l16 = lane & 15, quad = lane >> 4;
  const int wv = tid >> 6, wr = wv >> 1, wc = wv & 1;
  const int sr = tid >> 2, sc = (tid & 3) * 16;

  v4f acc[4][4];
  const v4f z4 = {0.f, 0.f, 0.f, 0.f};
  for (int i = 0; i < 4; ++i)
    for (int n = 0; n < 4; ++n) acc[i][n] = z4;

  for (int k0 = 0; k0 < kC; k0 += 64) {
    for (int p = 0; p < 2; ++p) {  // stage A (M operand)
      const int r = p * 64 + sr;
      v8s v0 = {0, 0, 0, 0, 0, 0, 0, 0}, v1 = v0;
      if (!vmode) {
        const int t = m0 + r;
        if (t < kRows) {
          const int bb = t / kN1, mm = t - bb * kN1;
          const float* s = x + ((size_t)(bb * 1026 + xoff + mm)) * kC + k0 + sc;
          const float4 f0 = *(const float4*)s;
          const float4 f1 = *(const float4*)(s + 4);
          const float4 f2 = *(const float4*)(s + 8);
          const float4 f3 = *(const float4*)(s + 12);
          v0 = (v8s){(short)f2b(f0.x), (short)f2b(f0.y), (short)f2b(f0.z),
                     (short)f2b(f0.w), (short)f2b(f1.x), (short)f2b(f1.y),
                     (short)f2b(f1.z), (short)f2b(f1.w)};
          v1 = (v8s){(short)f2b(f2.x), (short)f2b(f2.y), (short)f2b(f2.z),
                     (short)f2b(f2.w), (short)f2b(f3.x), (short)f2b(f3.y),
                     (short)f2b(f3.z), (short)f2b(f3.w)};
        }
      } else {
        const u16* s = Wt + (size_t)(m0 + r) * kC + k0 + sc;
        v0 = *(const v8s*)s;
        v1 = *(const v8s*)(s + 8);
      }
      *(v8s*)&As[r][sc] = v0;
      *(v8s*)&As[r][sc + 8] = v1;
    }
    for (int p = 0; p < 2; ++p) {  // stage B (N operand)
      const int r = p * 64 + sr;
      v8s v0 = {0, 0, 0, 0, 0, 0, 0, 0}, v1 = v0;
      if (!vmode) {
        const u16* s = Wt + (size_t)(n0 + r) * kC + k0 + sc;
        v0 = *(const v8s*)s;
        v1 = *(const v8s*)(s + 8);
      } else {
        const int t = n0 + r;
        if (t < kRows) {
          const int bb = t / kN1, mm = t - bb * kN1;
          const float* s = x + ((size_t)(bb * 1026 + xoff + mm)) * kC + k0 + sc;
          const float4 f0 = *(const float4*)s;
          const float4 f1 = *(const float4*)(s + 4);
          const float4 f2 = *(const float4*)(s + 8);
          const float4 f3 = *(const float4*)(s + 12);
          v0 = (v8s){(short)f2b(f0.x), (short)f2b(f0.y), (short)f2b(f0.z),
                     (short)f2b(f0.w), (short)f2b(f1.x), (short)f2b(f1.y),
                     (short)f2b(f1.z), (short)f2b(f1.w)};
          v1 = (v8s){(short)f2b(f2.x), (short)f2b(f2.y), (short)f2b(f2.z),
                     (short)f2b(f2.w), (short)f2b(f3.x), (short)f2b(f3.y),
                     (short)f2b(f3.z), (short)f2b(f3.w)};
        }
      }
      *(v8s*)&Bs[r][sc] = v0;
      *(v8s*)&Bs[r][sc + 8] = v1;
    }
    __syncthreads();
    for (int ks = 0; ks < 2; ++ks) {
      v8s af[4], bfr[4];
      for (int i = 0; i < 4; ++i)
        af[i] = *(const v8s*)&As[wr * 64 + i * 16 + l16][ks * 32 + quad * 8];
      for (int n = 0; n < 4; ++n)
        bfr[n] = *(const v8s*)&Bs[wc * 64 + n * 16 + l16][ks * 32 + quad * 8];
      for (int i = 0; i < 4; ++i)
        for (int n = 0; n < 4; ++n)
          acc[i][n] = __builtin_amdgcn_mfma_f32_16x16x32_bf16(af[i], bfr[n],
                                                              acc[i][n], 0, 0, 0);
    }
    __syncthreads();
  }

  if (!vmode) {
    u16* outp = (op == 0) ? Qb : Kb;
    const float osc = (op == 0) ? 0.125f : 1.0f;
    float bv4[4];
    for (int nt = 0; nt < 4; ++nt) bv4[nt] = bias[n0 + wc * 64 + nt * 16 + l16];
    for (int i = 0; i < 4; ++i) {
      const int rowb = m0 + wr * 64 + i * 16 + quad * 4;
      for (int r = 0; r < 4; ++r) {
        const int row = rowb + r;
        if (row >= kRows) continue;
        for (int nt = 0; nt < 4; ++nt) {
          const int col = n0 + wc * 64 + nt * 16 + l16;
          outp[(size_t)row * kC + col] = f2b((acc[i][nt][r] + bv4[nt]) * osc);
        }
      }
    }
  } else {
    u16* Vt = (op == 2) ? Vt1 : Vt2;
    for (int nt = 0; nt < 4; ++nt) {
      const int t = n0 + wc * 64 + nt * 16 + l16;  // token
      if (t >= kRows) continue;
      const int bb = t / kN1, mm = t - bb * kN1;
      for (int i = 0; i < 4; ++i) {
        const int colb = m0 + wr * 64 + i * 16 + quad * 4;
        for (int r = 0; r < 4; ++r) {
          const int col = colb + r;
          const int hh = col >> 6, d = col & 63;
          Vt[((size_t)(bb * kH + hh) * 64 + d) * kPld + mm] =
              f2b(acc[i][nt][r] + bias[col]);
        }
      }
    }
  }
}

// ---- phase: flash attention, one (q-tile 64, bh) unit; no-max softmax ----
__device__ __forceinline__ void phase_attn(u16* sm, int q0, int bh,
                                           const u16* Qb, const u16* Kb,
                                           const u16* Vt1, const u16* Vt2,
                                           u16* PRE) {
  u16 (*Ks)[72] = (u16(*)[72])sm;
  u16 (*Vs)[72] = (u16(*)[72])(sm + 4608);
  u16 (*Ps)[16][72] = (u16(*)[16][72])(sm + 13824);
  const int b = bh / kH, hh = bh - b * kH;
  const int tid = threadIdx.x;
  const int w = tid >> 6, lane = tid & 63, l16 = lane & 15, quad = lane >> 4;
  v8s aq0, aq1;
  {  // Q fragments straight from global (wave reads only its 16 rows)
    int qr = q0 + w * 16 + l16;
    if (qr > 512) qr = 512;  // clamp: dup row, results discarded at write
    const u16* qs = Qb + ((size_t)(b * kN1 + qr)) * kC + hh * 64 + quad * 8;
    aq0 = *(const v8s*)qs;
    aq1 = *(const v8s*)(qs + 32);
  }
  const int ksr = tid >> 2, ksc = (tid & 3) * 16;
  const int vd = tid >> 1, vc = (tid & 1) * 32;
  const u16* kbase = Kb + (size_t)b * kN1 * kC + hh * 64 + ksc;
  const u16* vbase = ((vd < 64) ? (Vt1 + ((size_t)bh * 64 + vd) * kPld)
                                : (Vt2 + ((size_t)bh * 64 + (vd - 64)) * kPld)) +
                     vc;
  v8s kr0, kr1, vr0, vr1, vr2, vr3;
  {  // prefetch kt=0
    const u16* s = kbase + (size_t)ksr * kC;
    kr0 = *(const v8s*)s;
    kr1 = *(const v8s*)(s + 8);
    vr0 = *(const v8s*)(vbase);
    vr1 = *(const v8s*)(vbase + 8);
    vr2 = *(const v8s*)(vbase + 16);
    vr3 = *(const v8s*)(vbase + 24);
  }
  float lsum[4] = {0.f, 0.f, 0.f, 0.f};
  v4f Oacc[8];
  const v4f z4 = {0.f, 0.f, 0.f, 0.f};
  for (int n = 0; n < 8; ++n) Oacc[n] = z4;

  for (int kt = 0; kt < 9; ++kt) {
    const int k0 = kt * 64;
    __syncthreads();  // prior iter's LDS reads complete
    *(v8s*)&Ks[ksr][ksc] = kr0;
    *(v8s*)&Ks[ksr][ksc + 8] = kr1;
    *(v8s*)&Vs[vd][vc] = vr0;
    *(v8s*)&Vs[vd][vc + 8] = vr1;
    *(v8s*)&Vs[vd][vc + 16] = vr2;
    *(v8s*)&Vs[vd][vc + 24] = vr3;
    __syncthreads();
    if (kt < 8) {  // register prefetch of kt+1, hidden under compute
      int ki = k0 + 64 + ksr;
      if (ki > 512) ki = 512;
      const u16* s = kbase + (size_t)ki * kC;
      kr0 = *(const v8s*)s;
      kr1 = *(const v8s*)(s + 8);
      const u16* t = vbase + k0 + 64;
      vr0 = *(const v8s*)t;
      vr1 = *(const v8s*)(t + 8);
      vr2 = *(const v8s*)(t + 16);
      vr3 = *(const v8s*)(t + 24);
    }
    v4f sacc[4];
    for (int nt = 0; nt < 4; ++nt) sacc[nt] = z4;
    for (int nt = 0; nt < 4; ++nt) {
      const v8s bk0 = *(const v8s*)&Ks[nt * 16 + l16][quad * 8];
      sacc[nt] = __builtin_amdgcn_mfma_f32_16x16x32_bf16(aq0, bk0, sacc[nt], 0, 0, 0);
      const v8s bk1 = *(const v8s*)&Ks[nt * 16 + l16][32 + quad * 8];
      sacc[nt] = __builtin_amdgcn_mfma_f32_16x16x32_bf16(aq1, bk1, sacc[nt], 0, 0, 0);
    }
    for (int r = 0; r < 4; ++r) {
      float ps = 0.f;
      for (int nt = 0; nt < 4; ++nt) {
        const int col = k0 + nt * 16 + l16;
        const float p = (col < kN1) ? __expf(sacc[nt][r]) : 0.f;
        ps += p;
        Ps[w][quad * 4 + r][nt * 16 + l16] = f2b(p);
      }
      lsum[r] += ps;
    }
    for (int kc = 0; kc < 2; ++kc) {
      const v8s ap = *(const v8s*)&Ps[w][l16][kc * 32 + quad * 8];
      for (int n = 0; n < 8; ++n) {
        const v8s bv = *(const v8s*)&Vs[n * 16 + l16][kc * 32 + quad * 8];
        Oacc[n] = __builtin_amdgcn_mfma_f32_16x16x32_bf16(ap, bv, Oacc[n], 0, 0, 0);
      }
    }
  }
  float rinv[4];
  for (int r = 0; r < 4; ++r) {
    float s = lsum[r];
    for (int o = 1; o <= 8; o <<= 1) s += __shfl_xor(s, o);
    rinv[r] = 1.f / s;
  }
  for (int n = 0; n < 8; ++n) {
    const int col = hh * 64 + (n & 3) * 16 + l16;
    const int rbase = b * 1026 + ((n < 4) ? 0 : kN1);
    for (int r = 0; r < 4; ++r) {
      const int q = q0 + w * 16 + quad * 4 + r;
      if (q >= kN1) continue;
      PRE[(size_t)(rbase + q) * kC + col] = f2b(Oacc[n][r] * rinv[r]);
    }
  }
  __syncthreads();  // LDS reuse safety for any following phase
}

// ---- phase: one 128x128 tile of OUT = PRE @ Wo + bo (fp32 out) ----
__device__ __forceinline__ void phase_out(u16* sm, int m0, int n0,
                                          const u16* PRE, const u16* Wot,
                                          const float* bo, float* OUT) {
  u16 (*As)[72] = (u16(*)[72])sm;
  u16 (*Bs)[72] = (u16(*)[72])(sm + 9216);
  const int tid = threadIdx.x;
  const int lane = tid & 63, l16 = lane & 15, quad = lane >> 4;
  const int wv = tid >> 6, wr = wv >> 1, wc = wv & 1;
  const int sr = tid >> 2, sc = (tid & 3) * 16;
  v4f acc[4][4];
  const v4f z4 = {0.f, 0.f, 0.f, 0.f};
  for (int i = 0; i < 4; ++i)
    for (int n = 0; n < 4; ++n) acc[i][n] = z4;
  for (int k0 = 0; k0 < kC; k0 += 64) {
    for (int p = 0; p < 2; ++p) {
      const int r = p * 64 + sr;
      v8s v0 = {0, 0, 0, 0, 0, 0, 0, 0}, v1 = v0;
      const int row = m0 + r;
      if (row < kRows2) {
        const u16* s = PRE + (size_t)row * kC + k0 + sc;
        v0 = *(const v8s*)s;
        v1 = *(const v8s*)(s + 8);
      }
      *(v8s*)&As[r][sc] = v0;
      *(v8s*)&As[r][sc + 8] = v1;
      const u16* s2 = Wot + (size_t)(n0 + r) * kC + k0 + sc;
      *(v8s*)&Bs[r][sc] = *(const v8s*)s2;
      *(v8s*)&Bs[r][sc + 8] = *(const v8s*)(s2 + 8);
    }
    __syncthreads();
    for (int ks = 0; ks < 2; ++ks) {
      v8s af[4], bfr[4];
      for (int i = 0; i < 4; ++i)
        af[i] = *(const v8s*)&As[wr * 64 + i * 16 + l16][ks * 32 + quad * 8];
      for (int n = 0; n < 4; ++n)
        bfr[n] = *(const v8s*)&Bs[wc * 64 + n * 16 + l16][ks * 32 + quad * 8];
      for (int i = 0; i < 4; ++i)
        for (int n = 0; n < 4; ++n)
          acc[i][n] = __builtin_amdgcn_mfma_f32_16x16x32_bf16(af[i], bfr[n],
                                                              acc[i][n], 0, 0, 0);
    }
    __syncthreads();
  }
  float bv4[4];
  for (int nt = 0; nt < 4; ++nt) bv4[nt] = bo[n0 + wc * 64 + nt * 16 + l16];
  for (int i = 0; i < 4; ++i) {
    const int rowb = m0 + wr * 64 + i * 16 + quad * 4;
    for (int r = 0; r < 4; ++r) {
      const int row = rowb + r;
      if (row >= kRows2) continue;
      for (int nt = 0; nt < 4; ++nt) {
        const int col = n0 + wc * 64 + nt * 16 + l16;
        OUT[(size_t)row * kC + col] = acc[i][nt][r] + bv4[nt];
      }
    }
  }
}

// ---- the cooperative mega-kernel: all 4 phases, 3 grid syncs ----
__global__ __launch_bounds__(256) void mega(
    const float* x, const float* Wq1, const float* bq1, const float* Wq2,
    const float* bq2, const float* Wk1, const float* bk1, const float* Wk2,
    const float* bk2, const float* Wv1, const float* bv1, const float* Wv2,
    const float* bv2, const float* Wo, const float* bo, const float* wts,
    const float* gum, float* OUT, u16* Wqt, u16* Wkt, u16* Wv1t, u16* Wv2t,
    u16* Wot, u16* Qb, u16* Kb, u16* Vt1, u16* Vt2, u16* PRE) {
  cg::grid_group grid = cg::this_grid();
  __shared__ __align__(16) u16 sm[18432];  // 36,864 B, reused per phase
  const int bid = blockIdx.x;
  const int j = gumbel_argmax(wts, gum);
  for (int u = bid; u < 720; u += kGrid)
    phase_prep(sm, u, Wq1, Wq2, Wk1, Wk2, Wv1, Wv2, Wo, j, Wqt, Wkt, Wv1t,
               Wv2t, Wot);
  __threadfence();
  grid.sync();
  if (bid < 396) {
    const int op = bid / 99, rem = bid - op * 99;
    phase_qkv(sm, op, rem % 33, rem / 33, x, Wqt, Wkt, Wv1t, Wv2t, bq1, bq2,
              bk1, bk2, bv1, bv2, j, Qb, Kb, Vt1, Vt2);
  }
  __threadfence();
  grid.sync();
  phase_attn(sm, (bid % 9) * 64, bid / 9, Qb, Kb, Vt1, Vt2, PRE);
  __threadfence();
  grid.sync();
  if (bid < 195)
    phase_out(sm, (bid % 65) * 128, (bid / 65) * 128, PRE, Wot, bo, OUT);
}

// ---- fallback wrappers (used only if cooperative launch is rejected) ----
__global__ __launch_bounds__(256) void k_prep(
    const float* Wq1, const float* Wq2, const float* Wk1, const float* Wk2,
    const float* Wv1, const float* Wv2, const float* Wo, const float* wts,
    const float* gum, u16* Wqt, u16* Wkt, u16* Wv1t, u16* Wv2t, u16* Wot) {
  __shared__ __align__(16) u16 sm[18432];
  phase_prep(sm, blockIdx.x, Wq1, Wq2, Wk1, Wk2, Wv1, Wv2, Wo,
             gumbel_argmax(wts, gum), Wqt, Wkt, Wv1t, Wv2t, Wot);
}
__global__ __launch_bounds__(256) void k_qkv(
    const float* x, const u16* Wqt, const u16* Wkt, const u16* Wv1t,
    const u16* Wv2t, const float* bq1, const float* bq2, const float* bk1,
    const float* bk2, const float* bv1, const float* bv2, const float* wts,
    const float* gum, u16* Qb, u16* Kb, u16* Vt1, u16* Vt2) {
  __shared__ __align__(16) u16 sm[18432];
  phase_qkv(sm, blockIdx.z, blockIdx.x, blockIdx.y, x, Wqt, Wkt, Wv1t, Wv2t,
            bq1, bq2, bk1, bk2, bv1, bv2, gumbel_argmax(wts, gum), Qb, Kb, Vt1,
            Vt2);
}
__global__ __launch_bounds__(256) void k_attn(const u16* Qb, const u16* Kb,
                                              const u16* Vt1, const u16* Vt2,
                                              u16* PRE) {
  __shared__ __align__(16) u16 sm[18432];
  phase_attn(sm, blockIdx.x * 64, blockIdx.y, Qb, Kb, Vt1, Vt2, PRE);
}
__global__ __launch_bounds__(256) void k_out(const u16* PRE, const u16* Wot,
                                             const float* bo, float* OUT) {
  __shared__ __align__(16) u16 sm[18432];
  phase_out(sm, blockIdx.x * 128, blockIdx.y * 128, PRE, Wot, bo, OUT);
}

extern "C" void kernel_launch(void* const* d_in, const int* in_sizes, int n_in,
                              void* d_out, int out_size, void* d_ws,
                              size_t ws_size, hipStream_t stream) {
  const float* x = (const float*)d_in[0];
  const float* Wq1 = (const float*)d_in[1];
  const float* bq1 = (const float*)d_in[2];
  const float* Wq2 = (const float*)d_in[3];
  const float* bq2 = (const float*)d_in[4];
  const float* Wk1 = (const float*)d_in[5];
  const float* bk1 = (const float*)d_in[6];
  const float* Wk2 = (const float*)d_in[7];
  const float* bk2 = (const float*)d_in[8];
  const float* Wv1 = (const float*)d_in[9];
  const float* bv1 = (const float*)d_in[10];
  const float* Wv2 = (const float*)d_in[11];
  const float* bv2 = (const float*)d_in[12];
  const float* Wo = (const float*)d_in[13];
  const float* bo = (const float*)d_in[14];
  const float* wts = (const float*)d_in[15];
  const float* gum = (const float*)d_in[16];
  float* OUT = (float*)d_out;

  u16* Wqt = (u16*)d_ws;                     // 147456 elems each
  u16* Wkt = Wqt + 147456;
  u16* Wv1t = Wkt + 147456;
  u16* Wv2t = Wv1t + 147456;
  u16* Wot = Wv2t + 147456;
  u16* Qb = Wot + 147456;                    // 4104*384
  u16* Kb = Qb + (size_t)kRows * kC;         // 4104*384
  u16* Vt1 = Kb + (size_t)kRows * kC;        // 48*64*576
  u16* Vt2 = Vt1 + (size_t)kBH * 64 * kPld;  // 48*64*576
  u16* PRE = Vt2 + (size_t)kBH * 64 * kPld;  // 8208*384

  void* args[] = {&x,   &Wq1, &bq1, &Wq2,  &bq2,  &Wk1, &bk1, &Wk2, &bk2, &Wv1,
                  &bv1, &Wv2, &bv2, &Wo,   &bo,   &wts, &gum, &OUT, &Wqt, &Wkt,
                  &Wv1t, &Wv2t, &Wot, &Qb, &Kb, &Vt1, &Vt2, &PRE};
  const hipError_t err = hipLaunchCooperativeKernel(
      (const void*)mega, dim3(kGrid), dim3(256), args, 0, stream);
  if (err != hipSuccess) {  // deterministic fallback: 4 plain launches
    k_prep<<<dim3(720), 256, 0, stream>>>(Wq1, Wq2, Wk1, Wk2, Wv1, Wv2, Wo,
                                          wts, gum, Wqt, Wkt, Wv1t, Wv2t, Wot);
    k_qkv<<<dim3(33, 3, 4), 256, 0, stream>>>(x, Wqt, Wkt, Wv1t, Wv2t, bq1,
                                              bq2, bk1, bk2, bv1, bv2, wts,
                                              gum, Qb, Kb, Vt1, Vt2);
    k_attn<<<dim3(9, kBH), 256, 0, stream>>>(Qb, Kb, Vt1, Vt2, PRE);
    k_out<<<dim3(65, 3), 256, 0, stream>>>(PRE, Wot, bo, OUT);
  }
}

// Round 7
// 148.190 us; speedup vs baseline: 3.2471x; 3.2471x over previous
//
#include <hip/hip_runtime.h>

typedef unsigned short u16;
typedef short v8s __attribute__((ext_vector_type(8)));
typedef float v4f __attribute__((ext_vector_type(4)));

namespace {
constexpr int kC = 384;
constexpr int kN1 = 513;
constexpr int kH = 6;
constexpr int kBH = 48;      // B*H
constexpr int kRows = 4104;  // B*N1 tokens per half
constexpr int kRows2 = 8208; // B*M
constexpr int kPld = 576;    // Vt k-stride in bf16 elems (64*9)
}  // namespace

__device__ __forceinline__ u16 f2b(float f) {
  unsigned int u = __float_as_uint(f);
  u += 0x7fffu + ((u >> 16) & 1u);
  return (u16)(u >> 16);
}

__device__ __forceinline__ int gumbel_argmax(const float* __restrict__ w,
                                             const float* __restrict__ g) {
  float v0 = w[0] + g[0], v1 = w[1] + g[1], v2 = w[2] + g[2], v3 = w[3] + g[3];
  int j = 0;
  float m = v0;
  if (v1 > m) { m = v1; j = 1; }
  if (v2 > m) { m = v2; j = 2; }
  if (v3 > m) { m = v3; j = 3; }
  return j;
}

// ---- weights-only prep: select + transpose + convert 5 weights to bf16 [n][k]
__global__ __launch_bounds__(256) void prep_w(
    const float* __restrict__ Wq1, const float* __restrict__ Wq2,
    const float* __restrict__ Wk1, const float* __restrict__ Wk2,
    const float* __restrict__ Wv1, const float* __restrict__ Wv2,
    const float* __restrict__ Wo, const float* __restrict__ wts,
    const float* __restrict__ gum, u16* __restrict__ Wqt,
    u16* __restrict__ Wkt, u16* __restrict__ Wv1t, u16* __restrict__ Wv2t,
    u16* __restrict__ Wot) {
  __shared__ float tb[32][33];
  const int bx = blockIdx.x;
  const int z = bx / 144, rem = bx - z * 144;
  const int c0 = (rem % 12) * 32, r0 = (rem / 12) * 32;
  const int j = gumbel_argmax(wts, gum);
  const float* src;
  u16* dst;
  switch (z) {
    case 0: src = (j < 2) ? Wq1 : Wq2; dst = Wqt; break;
    case 1: src = (j == 0 || j == 2) ? Wk1 : Wk2; dst = Wkt; break;
    case 2: src = Wv1; dst = Wv1t; break;
    case 3: src = Wv2; dst = Wv2t; break;
    default: src = Wo; dst = Wot; break;
  }
  const int tx = threadIdx.x & 31, ty = threadIdx.x >> 5;
  for (int p = 0; p < 4; ++p)
    tb[ty + p * 8][tx] = src[(size_t)(r0 + ty + p * 8) * kC + c0 + tx];
  __syncthreads();
  for (int p = 0; p < 4; ++p)
    dst[(size_t)(c0 + ty + p * 8) * kC + r0 + tx] = f2b(tb[tx][ty + p * 8]);
}

// ---- fused QKV projections, bf16 MFMA; x converted fp32->bf16 inline ----
// 1-D grid of 400: xcd=bid&7 pairs to op=xcd>>1, so each weight matrix stays
// L2-resident in 2 XCDs. w=(bid>>3)*2+(xcd&1) in [0,100); w>=99 idles.
// op0: Q = 0.125*(xsel @ Wq + bq); op1: K = xsel @ Wk + bk (natural layout)
// op2/3: Vt = (x @ Wv)^T written as Vt[bh][d][kPld] (swapped-operand MFMA)
__global__ __launch_bounds__(256) void qkv_mfma(
    const float* __restrict__ x, const u16* __restrict__ Wqt,
    const u16* __restrict__ Wkt, const u16* __restrict__ Wv1t,
    const u16* __restrict__ Wv2t, const float* __restrict__ bq1,
    const float* __restrict__ bq2, const float* __restrict__ bk1,
    const float* __restrict__ bk2, const float* __restrict__ bv1,
    const float* __restrict__ bv2, const float* __restrict__ wts,
    const float* __restrict__ gum, u16* __restrict__ Qb, u16* __restrict__ Kb,
    u16* __restrict__ Vt1, u16* __restrict__ Vt2) {
  const int bid = blockIdx.x;
  const int xcd = bid & 7;
  const int op = xcd >> 1;
  const int wu = (bid >> 3) * 2 + (xcd & 1);
  if (wu >= 99) return;
  const int mb33 = wu / 3, nb3 = wu - mb33 * 3;

  __shared__ __align__(16) u16 As[128][72];
  __shared__ __align__(16) u16 Bs[128][72];
  const int j = gumbel_argmax(wts, gum);
  const bool vmode = (op >= 2);
  const float* bias;
  int xoff;
  const u16* Wt;
  if (op == 0) {
    bias = (j < 2) ? bq1 : bq2; xoff = (j < 2) ? 0 : kN1; Wt = Wqt;
  } else if (op == 1) {
    const bool u1 = (j == 0 || j == 2);
    bias = u1 ? bk1 : bk2; xoff = u1 ? 0 : kN1; Wt = Wkt;
  } else if (op == 2) {
    bias = bv1; xoff = 0; Wt = Wv1t;
  } else {
    bias = bv2; xoff = kN1; Wt = Wv2t;
  }
  const int m0 = (vmode ? nb3 : mb33) * 128;
  const int n0 = (vmode ? mb33 : nb3) * 128;
  const int tid = threadIdx.x;
  const int lane = tid & 63, l16 = lane & 15, quad = lane >> 4;
  const int wv = tid >> 6, wr = wv >> 1, wc = wv & 1;
  const int sr = tid >> 2, sc = (tid & 3) * 16;

  v4f acc[4][4];
  const v4f z4 = {0.f, 0.f, 0.f, 0.f};
  for (int i = 0; i < 4; ++i)
    for (int n = 0; n < 4; ++n) acc[i][n] = z4;

  for (int k0 = 0; k0 < kC; k0 += 64) {
    for (int p = 0; p < 2; ++p) {  // stage A (M operand)
      const int r = p * 64 + sr;
      v8s v0 = {0, 0, 0, 0, 0, 0, 0, 0}, v1 = v0;
      if (!vmode) {
        const int t = m0 + r;
        if (t < kRows) {
          const int bb = t / kN1, mm = t - bb * kN1;
          const float* s = x + ((size_t)(bb * 1026 + xoff + mm)) * kC + k0 + sc;
          const float4 f0 = *(const float4*)s;
          const float4 f1 = *(const float4*)(s + 4);
          const float4 f2 = *(const float4*)(s + 8);
          const float4 f3 = *(const float4*)(s + 12);
          v0 = (v8s){(short)f2b(f0.x), (short)f2b(f0.y), (short)f2b(f0.z),
                     (short)f2b(f0.w), (short)f2b(f1.x), (short)f2b(f1.y),
                     (short)f2b(f1.z), (short)f2b(f1.w)};
          v1 = (v8s){(short)f2b(f2.x), (short)f2b(f2.y), (short)f2b(f2.z),
                     (short)f2b(f2.w), (short)f2b(f3.x), (short)f2b(f3.y),
                     (short)f2b(f3.z), (short)f2b(f3.w)};
        }
      } else {
        const u16* s = Wt + (size_t)(m0 + r) * kC + k0 + sc;
        v0 = *(const v8s*)s;
        v1 = *(const v8s*)(s + 8);
      }
      *(v8s*)&As[r][sc] = v0;
      *(v8s*)&As[r][sc + 8] = v1;
    }
    for (int p = 0; p < 2; ++p) {  // stage B (N operand)
      const int r = p * 64 + sr;
      v8s v0 = {0, 0, 0, 0, 0, 0, 0, 0}, v1 = v0;
      if (!vmode) {
        const u16* s = Wt + (size_t)(n0 + r) * kC + k0 + sc;
        v0 = *(const v8s*)s;
        v1 = *(const v8s*)(s + 8);
      } else {
        const int t = n0 + r;
        if (t < kRows) {
          const int bb = t / kN1, mm = t - bb * kN1;
          const float* s = x + ((size_t)(bb * 1026 + xoff + mm)) * kC + k0 + sc;
          const float4 f0 = *(const float4*)s;
          const float4 f1 = *(const float4*)(s + 4);
          const float4 f2 = *(const float4*)(s + 8);
          const float4 f3 = *(const float4*)(s + 12);
          v0 = (v8s){(short)f2b(f0.x), (short)f2b(f0.y), (short)f2b(f0.z),
                     (short)f2b(f0.w), (short)f2b(f1.x), (short)f2b(f1.y),
                     (short)f2b(f1.z), (short)f2b(f1.w)};
          v1 = (v8s){(short)f2b(f2.x), (short)f2b(f2.y), (short)f2b(f2.z),
                     (short)f2b(f2.w), (short)f2b(f3.x), (short)f2b(f3.y),
                     (short)f2b(f3.z), (short)f2b(f3.w)};
        }
      }
      *(v8s*)&Bs[r][sc] = v0;
      *(v8s*)&Bs[r][sc + 8] = v1;
    }
    __syncthreads();
    for (int ks = 0; ks < 2; ++ks) {
      v8s af[4], bfr[4];
      for (int i = 0; i < 4; ++i)
        af[i] = *(const v8s*)&As[wr * 64 + i * 16 + l16][ks * 32 + quad * 8];
      for (int n = 0; n < 4; ++n)
        bfr[n] = *(const v8s*)&Bs[wc * 64 + n * 16 + l16][ks * 32 + quad * 8];
      for (int i = 0; i < 4; ++i)
        for (int n = 0; n < 4; ++n)
          acc[i][n] = __builtin_amdgcn_mfma_f32_16x16x32_bf16(af[i], bfr[n],
                                                              acc[i][n], 0, 0, 0);
    }
    __syncthreads();
  }

  if (!vmode) {
    u16* outp = (op == 0) ? Qb : Kb;
    const float osc = (op == 0) ? 0.125f : 1.0f;
    float bv4[4];
    for (int nt = 0; nt < 4; ++nt) bv4[nt] = bias[n0 + wc * 64 + nt * 16 + l16];
    for (int i = 0; i < 4; ++i) {
      const int rowb = m0 + wr * 64 + i * 16 + quad * 4;
      for (int r = 0; r < 4; ++r) {
        const int row = rowb + r;
        if (row >= kRows) continue;
        for (int nt = 0; nt < 4; ++nt) {
          const int col = n0 + wc * 64 + nt * 16 + l16;
          outp[(size_t)row * kC + col] = f2b((acc[i][nt][r] + bv4[nt]) * osc);
        }
      }
    }
  } else {
    u16* Vt = (op == 2) ? Vt1 : Vt2;
    for (int nt = 0; nt < 4; ++nt) {
      const int t = n0 + wc * 64 + nt * 16 + l16;  // token
      if (t >= kRows) continue;
      const int bb = t / kN1, mm = t - bb * kN1;
      for (int i = 0; i < 4; ++i) {
        const int colb = m0 + wr * 64 + i * 16 + quad * 4;
        for (int r = 0; r < 4; ++r) {
          const int col = colb + r;
          const int hh = col >> 6, d = col & 63;
          Vt[((size_t)(bb * kH + hh) * 64 + d) * kPld + mm] =
              f2b(acc[i][nt][r] + bias[col]);
        }
      }
    }
  }
}

// ---- fused flash attention: Q-frags in registers, register-prefetched K/V,
//      no-max softmax. 1-D grid 432: xcd=bid&7, bh=xcd*6+(bid>>3)%6 so all 9
//      q-tiles of a head hit one XCD's L2 (6 heads = 3.8 MB < 4 MB L2).
__global__ __launch_bounds__(256) void attn_fused(const u16* __restrict__ Qb,
                                                  const u16* __restrict__ Kb,
                                                  const u16* __restrict__ Vt1,
                                                  const u16* __restrict__ Vt2,
                                                  u16* __restrict__ PRE) {
  __shared__ __align__(16) u16 Ks[64][72];
  __shared__ __align__(16) u16 Vs[128][72];
  __shared__ __align__(16) u16 Ps[4][16][72];
  const int bid = blockIdx.x;
  const int xcd = bid & 7;
  const int t6 = bid >> 3;           // 0..53
  const int bh = xcd * 6 + (t6 % 6); // 0..47
  const int q0 = (t6 / 6) * 64;      // 9 q-tiles
  const int b = bh / kH, hh = bh - b * kH;
  const int tid = threadIdx.x;
  const int w = tid >> 6, lane = tid & 63, l16 = lane & 15, quad = lane >> 4;
  v8s aq0, aq1;
  {  // Q fragments straight from global (each wave reads only its 16 rows)
    int qr = q0 + w * 16 + l16;
    if (qr > 512) qr = 512;  // clamp: dup row, results discarded at write
    const u16* qs = Qb + ((size_t)(b * kN1 + qr)) * kC + hh * 64 + quad * 8;
    aq0 = *(const v8s*)qs;
    aq1 = *(const v8s*)(qs + 32);
  }
  const int ksr = tid >> 2, ksc = (tid & 3) * 16;
  const int vd = tid >> 1, vc = (tid & 1) * 32;
  const u16* kbase = Kb + (size_t)b * kN1 * kC + hh * 64 + ksc;
  const u16* vbase = ((vd < 64) ? (Vt1 + ((size_t)bh * 64 + vd) * kPld)
                                : (Vt2 + ((size_t)bh * 64 + (vd - 64)) * kPld)) +
                     vc;
  v8s kr0, kr1, vr0, vr1, vr2, vr3;
  {  // prefetch kt=0
    const u16* s = kbase + (size_t)ksr * kC;
    kr0 = *(const v8s*)s;
    kr1 = *(const v8s*)(s + 8);
    vr0 = *(const v8s*)(vbase);
    vr1 = *(const v8s*)(vbase + 8);
    vr2 = *(const v8s*)(vbase + 16);
    vr3 = *(const v8s*)(vbase + 24);
  }
  float lsum[4] = {0.f, 0.f, 0.f, 0.f};
  v4f Oacc[8];
  const v4f z4 = {0.f, 0.f, 0.f, 0.f};
  for (int n = 0; n < 8; ++n) Oacc[n] = z4;

  for (int kt = 0; kt < 9; ++kt) {
    const int k0 = kt * 64;
    __syncthreads();  // prior iter's LDS reads complete
    *(v8s*)&Ks[ksr][ksc] = kr0;
    *(v8s*)&Ks[ksr][ksc + 8] = kr1;
    *(v8s*)&Vs[vd][vc] = vr0;
    *(v8s*)&Vs[vd][vc + 8] = vr1;
    *(v8s*)&Vs[vd][vc + 16] = vr2;
    *(v8s*)&Vs[vd][vc + 24] = vr3;
    __syncthreads();
    if (kt < 8) {  // register prefetch of kt+1, hidden under compute
      int ki = k0 + 64 + ksr;
      if (ki > 512) ki = 512;  // masked in exp; avoids OOB
      const u16* s = kbase + (size_t)ki * kC;
      kr0 = *(const v8s*)s;
      kr1 = *(const v8s*)(s + 8);
      const u16* t = vbase + k0 + 64;  // pad cols finite poison, P=0 kills them
      vr0 = *(const v8s*)t;
      vr1 = *(const v8s*)(t + 8);
      vr2 = *(const v8s*)(t + 16);
      vr3 = *(const v8s*)(t + 24);
    }
    v4f sacc[4];
    for (int nt = 0; nt < 4; ++nt) sacc[nt] = z4;
    for (int nt = 0; nt < 4; ++nt) {
      const v8s bk0 = *(const v8s*)&Ks[nt * 16 + l16][quad * 8];
      sacc[nt] = __builtin_amdgcn_mfma_f32_16x16x32_bf16(aq0, bk0, sacc[nt], 0, 0, 0);
      const v8s bk1 = *(const v8s*)&Ks[nt * 16 + l16][32 + quad * 8];
      sacc[nt] = __builtin_amdgcn_mfma_f32_16x16x32_bf16(aq1, bk1, sacc[nt], 0, 0, 0);
    }
    for (int r = 0; r < 4; ++r) {
      float ps = 0.f;
      for (int nt = 0; nt < 4; ++nt) {
        const int col = k0 + nt * 16 + l16;
        const float p = (col < kN1) ? __expf(sacc[nt][r]) : 0.f;
        ps += p;
        Ps[w][quad * 4 + r][nt * 16 + l16] = f2b(p);
      }
      lsum[r] += ps;
    }
    for (int kc = 0; kc < 2; ++kc) {
      const v8s ap = *(const v8s*)&Ps[w][l16][kc * 32 + quad * 8];
      for (int n = 0; n < 8; ++n) {
        const v8s bv = *(const v8s*)&Vs[n * 16 + l16][kc * 32 + quad * 8];
        Oacc[n] = __builtin_amdgcn_mfma_f32_16x16x32_bf16(ap, bv, Oacc[n], 0, 0, 0);
      }
    }
  }
  float rinv[4];
  for (int r = 0; r < 4; ++r) {
    float s = lsum[r];
    for (int o = 1; o <= 8; o <<= 1) s += __shfl_xor(s, o);
    rinv[r] = 1.f / s;
  }
  for (int n = 0; n < 8; ++n) {
    const int col = hh * 64 + (n & 3) * 16 + l16;
    const int rbase = b * 1026 + ((n < 4) ? 0 : kN1);
    for (int r = 0; r < 4; ++r) {
      const int q = q0 + w * 16 + quad * 4 + r;
      if (q >= kN1) continue;
      PRE[(size_t)(rbase + q) * kC + col] = f2b(Oacc[n][r] * rinv[r]);
    }
  }
}

// ---- OUT = PRE @ Wo + bo (fp32 out) ----
__global__ __launch_bounds__(256) void out_mfma(const u16* __restrict__ PRE,
                                                const u16* __restrict__ Wot,
                                                const float* __restrict__ bo,
                                                float* __restrict__ OUT) {
  __shared__ __align__(16) u16 As[128][72];
  __shared__ __align__(16) u16 Bs[128][72];
  const int m0 = blockIdx.x * 128, n0 = blockIdx.y * 128;
  const int tid = threadIdx.x;
  const int lane = tid & 63, l16 = lane & 15, quad = lane >> 4;
  const int wv = tid >> 6, wr = wv >> 1, wc = wv & 1;
  const int sr = tid >> 2, sc = (tid & 3) * 16;
  v4f acc[4][4];
  const v4f z4 = {0.f, 0.f, 0.f, 0.f};
  for (int i = 0; i < 4; ++i)
    for (int n = 0; n < 4; ++n) acc[i][n] = z4;
  for (int k0 = 0; k0 < kC; k0 += 64) {
    for (int p = 0; p < 2; ++p) {
      const int r = p * 64 + sr;
      v8s v0 = {0, 0, 0, 0, 0, 0, 0, 0}, v1 = v0;
      const int row = m0 + r;
      if (row < kRows2) {
        const u16* s = PRE + (size_t)row * kC + k0 + sc;
        v0 = *(const v8s*)s;
        v1 = *(const v8s*)(s + 8);
      }
      *(v8s*)&As[r][sc] = v0;
      *(v8s*)&As[r][sc + 8] = v1;
      const u16* s2 = Wot + (size_t)(n0 + r) * kC + k0 + sc;
      *(v8s*)&Bs[r][sc] = *(const v8s*)s2;
      *(v8s*)&Bs[r][sc + 8] = *(const v8s*)(s2 + 8);
    }
    __syncthreads();
    for (int ks = 0; ks < 2; ++ks) {
      v8s af[4], bfr[4];
      for (int i = 0; i < 4; ++i)
        af[i] = *(const v8s*)&As[wr * 64 + i * 16 + l16][ks * 32 + quad * 8];
      for (int n = 0; n < 4; ++n)
        bfr[n] = *(const v8s*)&Bs[wc * 64 + n * 16 + l16][ks * 32 + quad * 8];
      for (int i = 0; i < 4; ++i)
        for (int n = 0; n < 4; ++n)
          acc[i][n] = __builtin_amdgcn_mfma_f32_16x16x32_bf16(af[i], bfr[n],
                                                              acc[i][n], 0, 0, 0);
    }
    __syncthreads();
  }
  float bv4[4];
  for (int nt = 0; nt < 4; ++nt) bv4[nt] = bo[n0 + wc * 64 + nt * 16 + l16];
  for (int i = 0; i < 4; ++i) {
    const int rowb = m0 + wr * 64 + i * 16 + quad * 4;
    for (int r = 0; r < 4; ++r) {
      const int row = rowb + r;
      if (row >= kRows2) continue;
      for (int nt = 0; nt < 4; ++nt) {
        const int col = n0 + wc * 64 + nt * 16 + l16;
        OUT[(size_t)row * kC + col] = acc[i][nt][r] + bv4[nt];
      }
    }
  }
}

extern "C" void kernel_launch(void* const* d_in, const int* in_sizes, int n_in,
                              void* d_out, int out_size, void* d_ws,
                              size_t ws_size, hipStream_t stream) {
  const float* x = (const float*)d_in[0];
  const float* Wq1 = (const float*)d_in[1];
  const float* bq1 = (const float*)d_in[2];
  const float* Wq2 = (const float*)d_in[3];
  const float* bq2 = (const float*)d_in[4];
  const float* Wk1 = (const float*)d_in[5];
  const float* bk1 = (const float*)d_in[6];
  const float* Wk2 = (const float*)d_in[7];
  const float* bk2 = (const float*)d_in[8];
  const float* Wv1 = (const float*)d_in[9];
  const float* bv1 = (const float*)d_in[10];
  const float* Wv2 = (const float*)d_in[11];
  const float* bv2 = (const float*)d_in[12];
  const float* Wo = (const float*)d_in[13];
  const float* bo = (const float*)d_in[14];
  const float* wts = (const float*)d_in[15];
  const float* gum = (const float*)d_in[16];

  u16* Wqt = (u16*)d_ws;                         // 147456 elems each
  u16* Wkt = Wqt + 147456;
  u16* Wv1t = Wkt + 147456;
  u16* Wv2t = Wv1t + 147456;
  u16* Wot = Wv2t + 147456;
  u16* Qb = Wot + 147456;                        // 4104*384
  u16* Kb = Qb + (size_t)kRows * kC;             // 4104*384
  u16* Vt1 = Kb + (size_t)kRows * kC;            // 48*64*576
  u16* Vt2 = Vt1 + (size_t)kBH * 64 * kPld;      // 48*64*576
  u16* PRE = Vt2 + (size_t)kBH * 64 * kPld;      // 8208*384
  // total ~18 MB of d_ws

  prep_w<<<dim3(720), 256, 0, stream>>>(Wq1, Wq2, Wk1, Wk2, Wv1, Wv2, Wo, wts,
                                        gum, Wqt, Wkt, Wv1t, Wv2t, Wot);
  qkv_mfma<<<dim3(400), 256, 0, stream>>>(
      x, Wqt, Wkt, Wv1t, Wv2t, bq1, bq2, bk1, bk2, bv1, bv2, wts, gum, Qb, Kb,
      Vt1, Vt2);
  attn_fused<<<dim3(432), 256, 0, stream>>>(Qb, Kb, Vt1, Vt2, PRE);
  out_mfma<<<dim3(65, 3), 256, 0, stream>>>(PRE, Wot, bo, (float*)d_out);
}